// Round 1
// baseline (281.789 us; speedup 1.0000x reference)
//
#include <hip/hip_runtime.h>
#include <math.h>

#define BB 4
#define NN 512
#define DD 64
#define EPS 1e-5f
#define NEG_SLOPE 0.01f
#define TI 4   // i-rows per block in attn_kernel (one wave per row for softmax)

typedef float f32x4 __attribute__((ext_vector_type(4)));

// Kernel A: per-row LayerNorm folded into the two projections.
// One wave (64 lanes) per row; lane d holds i_em[row, d].
__global__ void __launch_bounds__(256)
stats_kernel(const float* __restrict__ i_em,
             const float* __restrict__ W_a,
             const float* __restrict__ gamma,
             const float* __restrict__ beta,
             float* __restrict__ sq,
             float* __restrict__ sk) {
    int row  = (blockIdx.x * blockDim.x + threadIdx.x) >> 6;   // global wave id
    int lane = threadIdx.x & 63;
    if (row >= BB * NN) return;

    float x = i_em[row * DD + lane];

    float s = x;
    #pragma unroll
    for (int off = 32; off >= 1; off >>= 1) s += __shfl_xor(s, off, 64);
    float mu = s * (1.0f / DD);

    float dx = x - mu;
    float v = dx * dx;
    #pragma unroll
    for (int off = 32; off >= 1; off >>= 1) v += __shfl_xor(v, off, 64);
    float rstd = rsqrtf(v * (1.0f / DD) + EPS);

    float xn = dx * rstd * gamma[lane] + beta[lane];
    float pq = xn * W_a[lane];
    float pk = xn * W_a[DD + lane];
    #pragma unroll
    for (int off = 32; off >= 1; off >>= 1) {
        pq += __shfl_xor(pq, off, 64);
        pk += __shfl_xor(pk, off, 64);
    }
    if (lane == 0) { sq[row] = pq; sk[row] = pk; }
}

// Kernel B: one block per TI=4 consecutive rows (b, i0..i0+3).
// Phase 1: softmax, one wave per row (no LDS, no barriers).
// Phase 2: value[b,i,j,:] = i_em[b,i,:] * i_em[b,j,:]; each xj load feeds
//          TI row-stores (load:store = 1:4), stores are non-temporal so the
//          256 MiB write stream doesn't evict the L2-resident i_em slice.
__global__ void __launch_bounds__(256)
attn_kernel(const float* __restrict__ i_em,
            const float* __restrict__ sq,
            const float* __restrict__ sk,
            const float* __restrict__ b_a,
            float* __restrict__ alphas,
            float* __restrict__ value) {
    const int blk  = blockIdx.x;
    const int i0g  = blk * TI;        // global row base (b*NN + i0)
    const int b    = i0g >> 9;        // / NN
    const int t    = threadIdx.x;
    const int lane = t & 63;
    const int w    = t >> 6;          // wave id == row offset r

    const float bias = b_a[0];

    // ---- phase 1: softmax over j, one wave per row ----
    {
        const int row  = i0g + w;                 // global row (b*NN + i)
        const float si = sq[row] + bias;
        const float* skb = sk + b * NN;

        float e[8];
        float m = -INFINITY;
        #pragma unroll
        for (int k = 0; k < 8; ++k) {
            float s = si + skb[lane + k * 64];
            s = (s >= 0.f) ? s : NEG_SLOPE * s;
            e[k] = s;
            m = fmaxf(m, s);
        }
        #pragma unroll
        for (int off = 32; off >= 1; off >>= 1) m = fmaxf(m, __shfl_xor(m, off, 64));

        float sum = 0.f;
        #pragma unroll
        for (int k = 0; k < 8; ++k) { e[k] = expf(e[k] - m); sum += e[k]; }
        #pragma unroll
        for (int off = 32; off >= 1; off >>= 1) sum += __shfl_xor(sum, off, 64);
        const float inv = 1.0f / sum;

        float* arow = alphas + (size_t)row * NN;
        #pragma unroll
        for (int k = 0; k < 8; ++k)
            __builtin_nontemporal_store(e[k] * inv, &arow[lane + k * 64]);
    }

    // ---- phase 2: outer-product value writes ----
    const f32x4* em4 = (const f32x4*)i_em;
    const int d4 = t & 15;            // which float4 of D=64
    const int jg = t >> 4;            // j group 0..15
    const f32x4* emb = em4 + (size_t)b * NN * 16;

    f32x4 xi[TI];
    #pragma unroll
    for (int r = 0; r < TI; ++r) xi[r] = em4[(size_t)(i0g + r) * 16 + d4];

    f32x4* out0 = (f32x4*)value + (size_t)i0g * (NN * 16) + d4;

    #pragma unroll 4
    for (int k = 0; k < NN / 16; ++k) {
        const int j = jg + k * 16;
        const f32x4 xj = emb[j * 16 + d4];   // L2-hit; 1 load feeds TI stores
        #pragma unroll
        for (int r = 0; r < TI; ++r) {
            f32x4 o = xi[r] * xj;
            __builtin_nontemporal_store(o, out0 + (size_t)r * (NN * 16) + j * 16);
        }
    }
}

extern "C" void kernel_launch(void* const* d_in, const int* in_sizes, int n_in,
                              void* d_out, int out_size, void* d_ws, size_t ws_size,
                              hipStream_t stream) {
    const float* i_em  = (const float*)d_in[0];
    const float* W_a   = (const float*)d_in[1];
    const float* b_a   = (const float*)d_in[2];
    const float* gamma = (const float*)d_in[3];
    const float* beta  = (const float*)d_in[4];

    float* alphas = (float*)d_out;                        // B*N*N
    float* value  = (float*)d_out + (size_t)BB * NN * NN; // B*N*N*D

    float* sq = (float*)d_ws;          // B*N
    float* sk = sq + BB * NN;          // B*N

    // 2048 rows, 4 waves per 256-thread block -> 512 blocks
    stats_kernel<<<(BB * NN) / 4, 256, 0, stream>>>(i_em, W_a, gamma, beta, sq, sk);
    // one block per TI=4 rows -> 512 blocks
    attn_kernel<<<(BB * NN) / TI, 256, 0, stream>>>(i_em, sq, sk, b_a, alphas, value);
}